// Round 5
// baseline (15.245 us; speedup 1.0000x reference)
//
#include <hip/hip_runtime.h>
#include <math.h>

#define NN 256
#define PP 32640        // N*(N-1)/2
#define HH 64
#define BB 32
#define NF4 (PP / 4)    // 8160 float4 per row

// Single fused kernel, one block per batch, 1024 threads, ZERO LDS atomics
// on the hot path (R3's mistake was a 21K-atomic LDS histogram; R4 proved:
//   sum(deg)  = 2 * count(dec==1)
//   #(deg==0) = 256 - popcount(OR of touched-node mask)
// ).
//
// Algebraic collapse (verified absmax 0.0 across R1-R4): GCN graph is the
// complete digraph + self-loops => norm = 1/256, conv outputs node-
// independent; net reduces to a scalar scan + 4 tiny matvecs + sigmoid.
__global__ __launch_bounds__(1024) void gnn_fused(
    const float* __restrict__ x,
    const float* __restrict__ W1, const float* __restrict__ b1,
    const float* __restrict__ W2, const float* __restrict__ b2,
    const float* __restrict__ W3, const float* __restrict__ b3,
    const float* __restrict__ We1, const float* __restrict__ be1,
    const float* __restrict__ We2, const float* __restrict__ be2,
    float* __restrict__ out)
{
    const int b    = blockIdx.x;
    const int tid  = threadIdx.x;
    const int lane = tid & 63;
    const int w    = tid >> 6;

    __shared__ unsigned char touched[NN];
    __shared__ float gS[HH];
    __shared__ float pr[4][HH];
    __shared__ int   s_cur, s_cnt, s_pop;

    if (tid < NN) touched[tid] = 0;
    if (tid == 0) { s_cur = 0; s_cnt = 0; s_pop = 0; }
    __syncthreads();

    const float*  decp = x + (size_t)b * (2 * PP);
    const float4* dec4 = (const float4*)decp;
    const float4* ind4 = (const float4*)(decp + PP);

    // ---- scan: 8 coalesced float4 iterations per thread, no atomics ----
    int cnt = 0;
    for (int q = tid; q < NF4; q += 1024) {
        float4 d  = dec4[q];
        float4 iv = ind4[q];
        const int p0 = q * 4;

        // invert triu_indices once per float4: O(i) = i*(511-i)/2
        int i = (int)((511.0f - sqrtf(261121.0f - 8.0f * (float)p0)) * 0.5f);
        while (i * (511 - i) / 2 > p0) --i;
        while ((i + 1) * (510 - i) / 2 <= p0) ++i;
        int rowStart = i * (511 - i) / 2;

        float dv[4]  = {d.x, d.y, d.z, d.w};
        float ivv[4] = {iv.x, iv.y, iv.z, iv.w};
        #pragma unroll
        for (int u = 0; u < 4; ++u) {
            const int p = p0 + u;
            while (p - rowStart >= 255 - i) { ++i; rowStart = i * (511 - i) / 2; }
            if (ivv[u] > 0.5f) s_cur = p;          // one-hot: single writer
            if (dv[u] == 1.0f) {
                const int j = i + 1 + (p - rowStart);
                touched[i] = 1;                    // racy-identical: benign
                touched[j] = 1;
                ++cnt;
            }
        }
    }

    // per-wave count reduce -> 16 small atomics
    #pragma unroll
    for (int off = 32; off > 0; off >>= 1) cnt += __shfl_down(cnt, off);
    if (lane == 0) atomicAdd(&s_cnt, cnt);
    __syncthreads();

    // touched-mask popcount: waves 0-3 ballot their 64 nodes
    if (tid < NN) {
        unsigned long long m = __ballot(touched[tid] != 0);
        if (lane == 0) atomicAdd(&s_pop, __popcll(m));
    }
    __syncthreads();

    // ---- collapsed network ----
    const float f0 = (float)(2 * s_cnt) * (1.0f / 255.0f);  // sum(deg)/255
    const float f1 = (float)(NN - s_pop);                   // #(deg==0)

    if (tid < HH) {
        float s = f0 * W1[tid] + f1 * W1[HH + tid] + 2.0f * W1[2 * HH + tid];
        gS[tid] = fmaxf(s * (1.0f / 256.0f) + b1[tid], 0.0f);
    }
    __syncthreads();

    // g2 = relu(g1 @ W2 + b2), k split over waves 0-3 (16 k each)
    if (tid < 256) {
        float s = 0.0f;
        const float* Wp = W2 + (w * 16) * HH + lane;
        #pragma unroll
        for (int kk = 0; kk < 16; ++kk) s += gS[w * 16 + kk] * Wp[kk * HH];
        pr[w][lane] = s;
    }
    __syncthreads();
    if (tid < HH)
        gS[tid] = fmaxf(pr[0][tid] + pr[1][tid] + pr[2][tid] + pr[3][tid] + b2[tid], 0.0f);
    __syncthreads();

    // g3 = relu(g2 @ W3 + b3)
    if (tid < 256) {
        float s = 0.0f;
        const float* Wp = W3 + (w * 16) * HH + lane;
        #pragma unroll
        for (int kk = 0; kk < 16; ++kk) s += gS[w * 16 + kk] * Wp[kk * HH];
        pr[w][lane] = s;
    }
    __syncthreads();
    if (tid < HH)
        gS[tid] = fmaxf(pr[0][tid] + pr[1][tid] + pr[2][tid] + pr[3][tid] + b3[tid], 0.0f);
    __syncthreads();

    // hm = relu([g3,g3,e0,e1,1] @ We1 + be1), We1 h-rows summed on the fly
    if (tid < 256) {
        float s = 0.0f;
        const float* Wa = We1 + (w * 16) * HH + lane;
        const float* Wb = We1 + (64 + w * 16) * HH + lane;
        #pragma unroll
        for (int kk = 0; kk < 16; ++kk)
            s += gS[w * 16 + kk] * (Wa[kk * HH] + Wb[kk * HH]);
        pr[w][lane] = s;
    }
    __syncthreads();
    if (tid < HH) {   // exactly wave 0
        const float dcur = decp[s_cur];            // broadcast load
        const float e0 = (dcur == 1.0f) ? 1.0f : 0.0f;
        const float e1 = (dcur != 0.5f) ? 1.0f : 0.0f;
        float v = pr[0][tid] + pr[1][tid] + pr[2][tid] + pr[3][tid] + be1[tid]
                + e0 * We1[128 * HH + tid] + e1 * We1[129 * HH + tid]
                + We1[130 * HH + tid];
        v = fmaxf(v, 0.0f);

        float contrib = v * We2[tid];
        #pragma unroll
        for (int off = 32; off > 0; off >>= 1)
            contrib += __shfl_down(contrib, off);

        if (tid == 0) {
            const float sig = 1.0f / (1.0f + expf(-(contrib + be2[0])));
            out[b * 2 + 0] = sig;
            out[b * 2 + 1] = sig;
        }
    }
}

extern "C" void kernel_launch(void* const* d_in, const int* in_sizes, int n_in,
                              void* d_out, int out_size, void* d_ws, size_t ws_size,
                              hipStream_t stream) {
    const float* x   = (const float*)d_in[0];
    const float* W1  = (const float*)d_in[1];
    const float* b1  = (const float*)d_in[2];
    const float* W2  = (const float*)d_in[3];
    const float* b2  = (const float*)d_in[4];
    const float* W3  = (const float*)d_in[5];
    const float* b3  = (const float*)d_in[6];
    const float* We1 = (const float*)d_in[7];
    const float* be1 = (const float*)d_in[8];
    const float* We2 = (const float*)d_in[9];
    const float* be2 = (const float*)d_in[10];
    float* out = (float*)d_out;

    gnn_fused<<<BB, 1024, 0, stream>>>(x, W1, b1, W2, b2, W3, b3,
                                       We1, be1, We2, be2, out);
}